// Round 15
// baseline (85.547 us; speedup 1.0000x reference)
//
#include <hip/hip_runtime.h>
#include <math.h>

#define NWIRES 6
#define DIM 64
#define NTOK 32768            // B*T = 16*2048
#define NBATCH 16
#define NMOM 16               // Taylor order: exp(az), |az|<=sqrt(6); rem ~8e-8
#define SQRT6F 2.4494897427831781f
#define APAD 76               // LDS row stride (ushorts), conflict-benign (R12)

typedef short bf16x8 __attribute__((ext_vector_type(8)));
typedef float f32x4  __attribute__((ext_vector_type(4)));

__device__ __forceinline__ unsigned f2bfbits(float f) {   // RNE fp32->bf16 bits
    unsigned u = __float_as_uint(f);
    return (u + 0x7FFF + ((u >> 16) & 1)) >> 16;
}
__device__ __forceinline__ float bfbits2f(unsigned b) {
    return __uint_as_float(b << 16);
}
__device__ __forceinline__ float pswap(float v) { return __shfl_xor(v, 1, 64); }

// ---------------------------------------------------------------------------
// A-build (R13/R14-verified): tables + A = [A_c; A_s] bf16 hi/lo into LDS.
// Thread (ph=tid>>7, k=(tid>>1)&63, h=tid&1) evolves a 32-float half-column
// via the lane-pair-split cascade.  Syncs fore and aft.
// ---------------------------------------------------------------------------
__device__ __forceinline__ void build_A(
        int tid, const float* __restrict__ p,
        float* sTc, float* sTs, float* sP,
        unsigned short* sAh, unsigned short* sAl) {
    __syncthreads();                      // prior users of tables/A are done
    if (tid < 64) {
        int b = tid;
        float d = 0.f;
#pragma unroll
        for (int j = 0; j < 6; ++j)
            d += 0.5f * p[j] * ((b & (32 >> j)) ? -1.f : 1.f);
        float sd, cd;
        sincosf(d, &sd, &cd);
        sTc[b] = cd;
        sTs[b] = sd;
        if (b < 12) {                     // p[6..11]=RY0, p[12..17]=RY1
            float s, cc;
            sincosf(0.5f * p[6 + b], &s, &cc);
            sP[b * 2 + 0] = cc;
            sP[b * 2 + 1] = s;
        }
    }
    __syncthreads();

    int ph = tid >> 7;                    // 0: cos rows, 1: sin rows
    int k  = (tid >> 1) & 63;             // column
    int h  = tid & 1;                     // bit5 (value 32) of row index
    const float* sTx = ph ? sTs : sTc;
    float v[32];
#pragma unroll
    for (int i = 0; i < 32; ++i) {
        int g = h * 32 + i;
        v[i] = (__popc(g & k) & 1) ? -sTx[g] : sTx[g];   // diag(T) W e_k
    }
    // Walsh stage M=32 (split), then local stages
#pragma unroll
    for (int i = 0; i < 32; ++i) {
        float pv_ = pswap(v[i]);
        v[i] = h ? (pv_ - v[i]) : (v[i] + pv_);
    }
#pragma unroll
    for (int M = 16; M >= 1; M >>= 1) {
#pragma unroll
        for (int i = 0; i < 32; ++i) {
            if (i & M) continue;
            int j = i | M;
            float a = v[i], b = v[j];
            v[i] = a + b; v[j] = a - b;
        }
    }
    // RY0 then CNOT ring then RY1
#pragma unroll
    for (int layer = 0; layer < 2; ++layer) {
        const float* Pl = sP + layer * 12;
        {
            float c = Pl[0], ss = h ? Pl[1] : -Pl[1];
#pragma unroll
            for (int i = 0; i < 32; ++i) {
                float pv_ = pswap(v[i]);
                v[i] = c * v[i] + ss * pv_;
            }
        }
#pragma unroll
        for (int w = 1; w < 6; ++w) {
            int M = 32 >> w;
            float c = Pl[w * 2], s = Pl[w * 2 + 1];
#pragma unroll
            for (int i = 0; i < 32; ++i) {
                if (i & M) continue;
                int j = i | M;
                float a = v[i], b = v[j];
                v[i] = c * a - s * b;
                v[j] = s * a + c * b;
            }
        }
        if (layer == 0) {
#pragma unroll
            for (int i = 0; i < 16; ++i) {          // CNOT(0,1)
                int j = i | 16;
                float a = v[i], b = v[j];
                v[i] = h ? b : a;
                v[j] = h ? a : b;
            }
#pragma unroll
            for (int w = 1; w < 5; ++w) {           // CNOT(1,2)..(4,5)
                int MC = 32 >> w, MT = MC >> 1;
#pragma unroll
                for (int i = 0; i < 32; ++i) {
                    if (!(i & MC) || (i & MT)) continue;
                    int j = i | MT;
                    float t = v[i]; v[i] = v[j]; v[j] = t;
                }
            }
#pragma unroll
            for (int i = 1; i < 32; i += 2) v[i] = pswap(v[i]);  // CNOT(5,0)
        }
    }
#pragma unroll
    for (int i = 0; i < 32; ++i) {
        int row = ph * 64 + h * 32 + i;
        unsigned hb = f2bfbits(v[i]);
        unsigned lb = f2bfbits(v[i] - bfbits2f(hb));
        sAh[row * APAD + k] = (unsigned short)hb;
        sAl[row * APAD + k] = (unsigned short)lb;
    }
    __syncthreads();
}

// ---------------------------------------------------------------------------
// MFMA pass over a 128-token tile (2 chunks of 16 tokens per wave).
// R14-verified fragment layouts, bf16x3 split, masked-sum epilogue.
// MODE 0: q  -> zq[t] = sqrt6*z0 (global). MODE 1: k -> zkv[tok*8] = z0 (LDS).
// MODE 2: v  -> zkv[tok*8+1..6] = z0..z5 (LDS).
// ---------------------------------------------------------------------------
template<int MODE>
__device__ __forceinline__ void mfma_pass(
        int tid, const float* __restrict__ x, int tbase,
        const unsigned short* sAh, const unsigned short* sAl,
        float* __restrict__ zq, float* zkv) {
    int lane = tid & 63, wv = tid >> 6;
    int q4 = lane >> 4, c16 = lane & 15;

    float4 rw[4];
    {
        const float* xr0 = x + ((size_t)(tbase + wv * 32 + c16)) * 64;
#pragma unroll
        for (int ks = 0; ks < 2; ++ks) {
            rw[ks * 2 + 0] = *(const float4*)(xr0 + ks * 32 + q4 * 8);
            rw[ks * 2 + 1] = *(const float4*)(xr0 + ks * 32 + q4 * 8 + 4);
        }
    }

    bf16x8 xh[2], xl[2];
#pragma unroll 1
    for (int cg = 0; cg < 2; ++cg) {
#pragma unroll
        for (int ks = 0; ks < 2; ++ks) {
            float4 f0 = rw[ks * 2], f1 = rw[ks * 2 + 1];
            float ff[8] = {f0.x, f0.y, f0.z, f0.w, f1.x, f1.y, f1.z, f1.w};
#pragma unroll
            for (int e = 0; e < 8; ++e) {
                unsigned hb = f2bfbits(ff[e]);
                unsigned lb = f2bfbits(ff[e] - bfbits2f(hb));
                xh[ks][e] = (short)hb;
                xl[ks][e] = (short)lb;
            }
        }
        int mytok = wv * 32 + cg * 16 + c16;
        if (cg < 1) {
            const float* xrn = x + ((size_t)(tbase + mytok + 16)) * 64;
#pragma unroll
            for (int ks = 0; ks < 2; ++ks) {
                rw[ks * 2 + 0] = *(const float4*)(xrn + ks * 32 + q4 * 8);
                rw[ks * 2 + 1] = *(const float4*)(xrn + ks * 32 + q4 * 8 + 4);
            }
        }

        f32x4 acc[8];
#pragma unroll
        for (int mt = 0; mt < 8; ++mt) acc[mt] = (f32x4){0.f, 0.f, 0.f, 0.f};
#pragma unroll
        for (int mt = 0; mt < 8; ++mt) {
            int r = mt * 16 + c16;               // A-op row m
#pragma unroll
            for (int ks = 0; ks < 2; ++ks) {
                const uint2* ph_ = (const uint2*)(&sAh[r * APAD + ks * 32 + q4 * 8]);
                const uint2* pl_ = (const uint2*)(&sAl[r * APAD + ks * 32 + q4 * 8]);
                union { uint2 u[2]; bf16x8 v; } ua, ub;
                ua.u[0] = ph_[0]; ua.u[1] = ph_[1];
                ub.u[0] = pl_[0]; ub.u[1] = pl_[1];
                bf16x8 ah = ua.v, al = ub.v;
                acc[mt] = __builtin_amdgcn_mfma_f32_16x16x32_bf16(ah, xh[ks], acc[mt], 0, 0, 0);
                acc[mt] = __builtin_amdgcn_mfma_f32_16x16x32_bf16(ah, xl[ks], acc[mt], 0, 0, 0);
                acc[mt] = __builtin_amdgcn_mfma_f32_16x16x32_bf16(al, xh[ks], acc[mt], 0, 0, 0);
            }
        }

        float n = 0.f, s0 = 0.f, s1 = 0.f, s2 = 0.f, s3 = 0.f, s4 = 0.f, s5 = 0.f;
        float f2 = (q4 < 2) ? 1.f : 0.f;         // r bit3 == 0
        float f3 = (q4 & 1) ? 0.f : 1.f;         // r bit2 == 0
#pragma unroll
        for (int mt = 0; mt < 4; ++mt) {
#pragma unroll
            for (int rg = 0; rg < 4; ++rg) {
                float dc = acc[mt][rg];          // row r = mt*16 + q4*4 + rg
                float ds = acc[mt + 4][rg];      // row r + 64
                float pp = dc * dc + ds * ds;
                n += pp;
                if (!(mt & 2)) s0 += pp;         // bit5
                if (!(mt & 1)) s1 += pp;         // bit4
                s2 += f2 * pp;                   // bit3
                s3 += f3 * pp;                   // bit2
                if (!(rg & 2)) s4 += pp;         // bit1
                if (!(rg & 1)) s5 += pp;         // bit0
            }
        }
#pragma unroll
        for (int d = 16; d <= 32; d <<= 1) {
            n  += __shfl_xor(n,  d, 64);
            s0 += __shfl_xor(s0, d, 64);
            s1 += __shfl_xor(s1, d, 64);
            s2 += __shfl_xor(s2, d, 64);
            s3 += __shfl_xor(s3, d, 64);
            s4 += __shfl_xor(s4, d, 64);
            s5 += __shfl_xor(s5, d, 64);
        }
        if (q4 == 0) {
            float inv = 1.0f / n;
            if (MODE == 0) {
                zq[tbase + mytok] = SQRT6F * (2.f * s0 - n) * inv;
            } else if (MODE == 1) {
                zkv[mytok * 8] = (2.f * s0 - n) * inv;
            } else {
                float* o = zkv + mytok * 8;
                o[1] = (2.f*s0 - n) * inv;
                o[2] = (2.f*s1 - n) * inv;
                o[3] = (2.f*s2 - n) * inv;
                o[4] = (2.f*s3 - n) * inv;
                o[5] = (2.f*s4 - n) * inv;
                o[6] = (2.f*s5 - n) * inv;
            }
        }
    }
}

// ---------------------------------------------------------------------------
// Kernel 1: fused sim.  Grid 512:
//  blocks 0..255   -> q circuit on tokens [bid*128, +128) -> zq (global)
//  blocks 256..511 -> k then v circuits (A rebuilt in same LDS) on tokens
//                     [(bid-256)*128); zk/zv parked in LDS; then the block
//                     computes its 112 moment partials in place -> mpart.
// Kills the moments kernel + node and the kv global round-trip (R14 post-
// mortem: fixed harness cost dominates; remaining levers are nodes/gaps/HBM).
// ---------------------------------------------------------------------------
__global__ __attribute__((amdgpu_waves_per_eu(1, 4)))
__launch_bounds__(256) void qsa_sim(
        const float* __restrict__ x,
        const float* __restrict__ pq,
        const float* __restrict__ pk,
        const float* __restrict__ pv,
        float* __restrict__ zq,
        float* __restrict__ mpart) {
    __shared__ unsigned short sAh[128 * APAD];   // 19456 B
    __shared__ unsigned short sAl[128 * APAD];   // 19456 B
    __shared__ float sTc[64], sTs[64], sP[24];
    __shared__ float zkv[128 * 8];               // 4 KB (kv blocks only)
    __shared__ float smom[4][56];                // per-wave moment partials
    int tid = threadIdx.x;
    int bid = blockIdx.x;

    if (bid < 256) {
        int tbase = bid * 128;
        build_A(tid, pq, sTc, sTs, sP, sAh, sAl);
        mfma_pass<0>(tid, x, tbase, sAh, sAl, zq, zkv);
        return;
    }

    int cc = bid - 256;                          // chunk id: 128 tokens each
    int tbase = cc * 128;
    build_A(tid, pk, sTc, sTs, sP, sAh, sAl);
    mfma_pass<1>(tid, x, tbase, sAh, sAl, zq, zkv);
    build_A(tid, pv, sTc, sTs, sP, sAh, sAl);    // leading sync guards zk/A
    mfma_pass<2>(tid, x, tbase, sAh, sAl, zq, zkv);
    __syncthreads();

    // ---- in-block moments: S_m = sum z^m, H_{m,w} = sum z^m v_w, m=0..15.
    // Thread = (token t = tid&127, moment-half = tid>>7). 64-lane butterfly
    // sums each wave's 64 tokens; waves {0,1}=half0, {2,3}=half1.
    {
        int t = tid & 127;
        int half = tid >> 7;
        int wv = tid >> 6, lane = tid & 63;
        const float* e = zkv + t * 8;
        float z = e[0];
        float v0 = e[1], v1 = e[2], v2 = e[3], v3 = e[4], v4 = e[5], v5 = e[6];
        float pw;
        if (half) { float z2 = z * z; float z4 = z2 * z2; pw = z4 * z4; }
        else pw = 1.f;
        float S[8], H[8][6];
#pragma unroll
        for (int m = 0; m < 8; ++m) {
            S[m] = pw;
            H[m][0] = pw * v0; H[m][1] = pw * v1; H[m][2] = pw * v2;
            H[m][3] = pw * v3; H[m][4] = pw * v4; H[m][5] = pw * v5;
            pw *= z;
        }
#pragma unroll
        for (int d = 32; d >= 1; d >>= 1) {
#pragma unroll
            for (int m = 0; m < 8; ++m) {
                S[m] += __shfl_xor(S[m], d, 64);
#pragma unroll
                for (int w = 0; w < 6; ++w) H[m][w] += __shfl_xor(H[m][w], d, 64);
            }
        }
        if (lane == 0) {
#pragma unroll
            for (int m = 0; m < 8; ++m) {
                smom[wv][m * 7 + 0] = S[m];
#pragma unroll
                for (int w = 0; w < 6; ++w) smom[wv][m * 7 + 1 + w] = H[m][w];
            }
        }
    }
    __syncthreads();
    if (tid < 112) {
        int m = tid / 7, comp = tid % 7;
        int half = m >> 3, ml = m & 7;
        float val = smom[half * 2 + 0][ml * 7 + comp]
                  + smom[half * 2 + 1][ml * 7 + comp];
        mpart[(size_t)cc * 112 + tid] = val;
    }
}

// ---------------------------------------------------------------------------
// Kernel 2: combine 16 chunk-partials per batch + per-token evaluation.
// den = sum_m p_m S_m, out_w = sum_m p_m H_mw, p_m = a^m/m!.
// ---------------------------------------------------------------------------
__global__ __launch_bounds__(256) void qsa_eval(
        const float* __restrict__ zq,
        const float* __restrict__ mpart,
        float* __restrict__ out) {
    __shared__ float sm[112];
    int bk = blockIdx.x;                      // 128 blocks of 256 tokens
    int b = bk >> 3;                          // 8 blocks per batch
    int tid = threadIdx.x;
    if (tid < 112) {
        float s = 0.f;
#pragma unroll
        for (int c = 0; c < 16; ++c)
            s += mpart[(size_t)(b * 16 + c) * 112 + tid];
        sm[tid] = s;
    }
    __syncthreads();

    int t = bk * 256 + tid;
    float a = zq[t];
    float den = 0.f, o0 = 0.f, o1 = 0.f, o2 = 0.f, o3 = 0.f, o4 = 0.f, o5 = 0.f;
    float pw = 1.f;
#pragma unroll
    for (int m = 0; m < NMOM; ++m) {
        const float* mm = sm + m * 7;
        den += pw * mm[0];
        o0 += pw * mm[1]; o1 += pw * mm[2]; o2 += pw * mm[3];
        o3 += pw * mm[4]; o4 += pw * mm[5]; o5 += pw * mm[6];
        pw *= a * (1.0f / (m + 1));           // p_{m+1} = p_m * a/(m+1)
    }
    float inv = 1.0f / den;
    float* o = out + (size_t)t * 6;
    float2* o2p = (float2*)o;                 // t*24B is 8-aligned
    o2p[0] = make_float2(o0 * inv, o1 * inv);
    o2p[1] = make_float2(o2 * inv, o3 * inv);
    o2p[2] = make_float2(o4 * inv, o5 * inv);
}

// ---------------------------------------------------------------------------
extern "C" void kernel_launch(void* const* d_in, const int* in_sizes, int n_in,
                              void* d_out, int out_size, void* d_ws, size_t ws_size,
                              hipStream_t stream) {
    const float* x  = (const float*)d_in[0];
    const float* pq = (const float*)d_in[1];
    const float* pk = (const float*)d_in[2];
    const float* pv = (const float*)d_in[3];
    float* w = (float*)d_ws;
    // ws (floats): zq[32768] | mpart[256*112]
    float* zq    = w;
    float* mpart = zq + NTOK;
    float* out   = (float*)d_out;

    qsa_sim<<<512, 256, 0, stream>>>(x, pq, pk, pv, zq, mpart);
    qsa_eval<<<NTOK / 256, 256, 0, stream>>>(zq, mpart, out);
}